// Round 3
// baseline (469.397 us; speedup 1.0000x reference)
//
#include <hip/hip_runtime.h>
#include <cfloat>
#include <cstddef>

#define BATCH 8
#define CDIM  256
#define NTOK  2304   // 48*48

typedef float    f32x4 __attribute__((ext_vector_type(4)));
typedef _Float16 f16x8 __attribute__((ext_vector_type(8)));
typedef _Float16 f16x4 __attribute__((ext_vector_type(4)));

#define MFMA16(a, b, c) __builtin_amdgcn_mfma_f32_16x16x32_f16(a, b, c, 0, 0, 0)

// ---------------------------------------------------------------------------
// Projection (fp32 math, fp16 store), o-tile = 256 (full C_OUT) x 64 n.
// mode 0: Q from x1 -> [B,N,C]; mode 1: K from x2 -> [B,N,C];
// mode 2: V from x2 -> [B,C,N].
// X tile is read ONCE per mode (was 4x in round 2).
// ---------------------------------------------------------------------------
__global__ __launch_bounds__(256) void proj_kernel(
    const float* __restrict__ x1, const float* __restrict__ x2,
    const float* __restrict__ Wq, const float* __restrict__ bq,
    const float* __restrict__ Wk, const float* __restrict__ bk,
    const float* __restrict__ Wv, const float* __restrict__ bv,
    _Float16* __restrict__ Qo, _Float16* __restrict__ Ko, _Float16* __restrict__ Vo)
{
    const int tid = threadIdx.x;
    const int tx = tid & 15, ty = tid >> 4;
    const int n0   = blockIdx.x * 64;
    const int mode = blockIdx.y;
    const int b    = blockIdx.z;

    const float* X    = (mode == 0) ? x1 : x2;
    const float* W    = (mode == 0) ? Wq : (mode == 1) ? Wk : Wv;
    const float* bias = (mode == 0) ? bq : (mode == 1) ? bk : bv;
    _Float16*    OUT  = (mode == 0) ? Qo : (mode == 1) ? Ko : Vo;

    __shared__ float Xs[16][64];
    __shared__ float Ws[16][260];   // [kc][o], transposed W

    float acc[4][4][4];   // [t: o-64-chunk][u: o within quad][n]
#pragma unroll
    for (int t = 0; t < 4; ++t)
#pragma unroll
        for (int u = 0; u < 4; ++u)
#pragma unroll
            for (int n = 0; n < 4; ++n) acc[t][u][n] = 0.f;

    for (int c0 = 0; c0 < CDIM; c0 += 16) {
        __syncthreads();
        // stage X tile [16 c][64 n], coalesced float4
        {
            float4 xv = *(const float4*)&X[(size_t)(b * CDIM + c0 + (tid >> 4)) * NTOK
                                           + n0 + (tid & 15) * 4];
            *(float4*)&Xs[tid >> 4][(tid & 15) * 4] = xv;
        }
        // stage W transposed: thread owns o = tid
#pragma unroll
        for (int u = 0; u < 4; ++u) {
            float4 wv = *(const float4*)&W[(size_t)tid * CDIM + c0 + u * 4];
            Ws[u * 4 + 0][tid] = wv.x;
            Ws[u * 4 + 1][tid] = wv.y;
            Ws[u * 4 + 2][tid] = wv.z;
            Ws[u * 4 + 3][tid] = wv.w;
        }
        __syncthreads();
#pragma unroll
        for (int kc = 0; kc < 16; ++kc) {
            float4 xv = *(const float4*)&Xs[kc][tx * 4];
#pragma unroll
            for (int t = 0; t < 4; ++t) {
                float4 wv = *(const float4*)&Ws[kc][ty * 4 + t * 64];
                acc[t][0][0] = fmaf(wv.x, xv.x, acc[t][0][0]);
                acc[t][0][1] = fmaf(wv.x, xv.y, acc[t][0][1]);
                acc[t][0][2] = fmaf(wv.x, xv.z, acc[t][0][2]);
                acc[t][0][3] = fmaf(wv.x, xv.w, acc[t][0][3]);
                acc[t][1][0] = fmaf(wv.y, xv.x, acc[t][1][0]);
                acc[t][1][1] = fmaf(wv.y, xv.y, acc[t][1][1]);
                acc[t][1][2] = fmaf(wv.y, xv.z, acc[t][1][2]);
                acc[t][1][3] = fmaf(wv.y, xv.w, acc[t][1][3]);
                acc[t][2][0] = fmaf(wv.z, xv.x, acc[t][2][0]);
                acc[t][2][1] = fmaf(wv.z, xv.y, acc[t][2][1]);
                acc[t][2][2] = fmaf(wv.z, xv.z, acc[t][2][2]);
                acc[t][2][3] = fmaf(wv.z, xv.w, acc[t][2][3]);
                acc[t][3][0] = fmaf(wv.w, xv.x, acc[t][3][0]);
                acc[t][3][1] = fmaf(wv.w, xv.y, acc[t][3][1]);
                acc[t][3][2] = fmaf(wv.w, xv.z, acc[t][3][2]);
                acc[t][3][3] = fmaf(wv.w, xv.w, acc[t][3][3]);
            }
        }
    }

    if (mode <= 1) {
        // [B, N, C]: per (t, n) store f16x4 spanning 4 consecutive o
#pragma unroll
        for (int t = 0; t < 4; ++t) {
            float4 bb = *(const float4*)&bias[t * 64 + ty * 4];
#pragma unroll
            for (int n = 0; n < 4; ++n) {
                f16x4 v = { (_Float16)(acc[t][0][n] + bb.x),
                            (_Float16)(acc[t][1][n] + bb.y),
                            (_Float16)(acc[t][2][n] + bb.z),
                            (_Float16)(acc[t][3][n] + bb.w) };
                *(f16x4*)&OUT[(size_t)(b * NTOK + n0 + tx * 4 + n) * CDIM
                              + t * 64 + ty * 4] = v;
            }
        }
    } else {
        // V: [B, C, N]: per (t, u) store f16x4 spanning 4 consecutive n
#pragma unroll
        for (int t = 0; t < 4; ++t) {
            float4 bb = *(const float4*)&bias[t * 64 + ty * 4];
#pragma unroll
            for (int u = 0; u < 4; ++u) {
                float bu = (u == 0) ? bb.x : (u == 1) ? bb.y : (u == 2) ? bb.z : bb.w;
                f16x4 v = { (_Float16)(acc[t][u][0] + bu),
                            (_Float16)(acc[t][u][1] + bu),
                            (_Float16)(acc[t][u][2] + bu),
                            (_Float16)(acc[t][u][3] + bu) };
                *(f16x4*)&OUT[(size_t)(b * CDIM + t * 64 + ty * 4 + u) * NTOK
                              + n0 + tx * 4] = v;
            }
        }
    }
}

// ---------------------------------------------------------------------------
// Split-KV MFMA flash attention. Waves fully independent (NO barriers).
// Each wave: 16 q-rows over one KV segment of NTOK/SEG positions.
// Q,K: [B,N,C] fp16; Vt: [B,C,N] fp16.
// Writes unnormalized partials: pacc [SEG][B][N][C] fp32, pml [SEG][B][N] float2(m,l).
// Fragment conventions identical to round 2 (HW-verified):
//   A: row=lane&15, k=(lane>>4)*8+e ; B: col=lane&15, k=(lane>>4)*8+e
//   D: col=lane&15, row=(lane>>4)*4+reg
// ---------------------------------------------------------------------------
template <int SEG>
__global__ __launch_bounds__(256, 2) void attn_fa(
    const _Float16* __restrict__ Q, const _Float16* __restrict__ K,
    const _Float16* __restrict__ Vt, float* __restrict__ pacc,
    float2* __restrict__ pml)
{
    const int tid  = threadIdx.x;
    const int lane = tid & 63;
    const int w    = tid >> 6;
    const int l15  = lane & 15, l4 = lane >> 4;

    // bijective XCD-chunked swizzle (nb % 8 == 0)
    const int nb  = 36 * BATCH * SEG, cpx = nb / 8;
    const int bid = blockIdx.x;
    const int swz = (bid & 7) * cpx + (bid >> 3);
    const int x = swz % 36;
    const int rest = swz / 36;
    const int b = rest & 7;
    const int z = rest >> 3;

    const int n0    = x * 64;
    const int row0  = n0 + w * 16;
    const int jbase = z * (NTOK / SEG);

    __shared__ __align__(16) _Float16 Pl[4][16 * 64];  // wave-private P tiles
    _Float16* Pw = Pl[w];

    // Q fragments: 16 rows x 256 c
    f16x8 qa[8];
    {
        const _Float16* qb = Q + ((size_t)b * NTOK + row0 + l15) * CDIM + l4 * 8;
#pragma unroll
        for (int kk = 0; kk < 8; ++kk) qa[kk] = *(const f16x8*)(qb + kk * 32);
    }

    f32x4 acc[16];
#pragma unroll
    for (int ct = 0; ct < 16; ++ct) acc[ct] = (f32x4){0.f, 0.f, 0.f, 0.f};
    float m[4] = {-FLT_MAX, -FLT_MAX, -FLT_MAX, -FLT_MAX};
    float l[4] = {0.f, 0.f, 0.f, 0.f};

    for (int jt = 0; jt < NTOK / SEG / 64; ++jt) {
        const int j0 = jbase + jt * 64;

        // ---- QK^T: S[16 i][64 j], K frags direct from global (L2) ----
        f32x4 s[4];
#pragma unroll
        for (int nt = 0; nt < 4; ++nt) {
            const _Float16* kb =
                K + ((size_t)b * NTOK + j0 + nt * 16 + l15) * CDIM + l4 * 8;
            f16x8 kf[8];
#pragma unroll
            for (int kk = 0; kk < 8; ++kk) kf[kk] = *(const f16x8*)(kb + kk * 32);
            f32x4 sv = (f32x4){0.f, 0.f, 0.f, 0.f};
#pragma unroll
            for (int kk = 0; kk < 8; ++kk) sv = MFMA16(qa[kk], kf[kk], sv);
            s[nt] = sv;
        }

        // ---- online softmax (rows i = 4*l4 + reg), defer-max THR=8 ----
#pragma unroll
        for (int reg = 0; reg < 4; ++reg) {
            float pm = fmaxf(fmaxf(s[0][reg], s[1][reg]),
                             fmaxf(s[2][reg], s[3][reg]));
            pm = fmaxf(pm, __shfl_xor(pm, 1));
            pm = fmaxf(pm, __shfl_xor(pm, 2));
            pm = fmaxf(pm, __shfl_xor(pm, 4));
            pm = fmaxf(pm, __shfl_xor(pm, 8));
            if (pm > m[reg] + 8.f) {
                float sc = __expf(m[reg] - pm);
                m[reg] = pm;
                l[reg] *= sc;
#pragma unroll
                for (int ct = 0; ct < 16; ++ct) acc[ct][reg] *= sc;
            }
            float ps = 0.f;
            const int r = 4 * l4 + reg;
#pragma unroll
            for (int nt = 0; nt < 4; ++nt) {
                float p = __expf(s[nt][reg] - m[reg]);
                ps += p;
                int j = nt * 16 + l15;
                int slot = (j >> 3) ^ (r & 7);
                Pw[r * 64 + slot * 8 + (j & 7)] = (_Float16)p;
            }
            ps += __shfl_xor(ps, 1);
            ps += __shfl_xor(ps, 2);
            ps += __shfl_xor(ps, 4);
            ps += __shfl_xor(ps, 8);
            l[reg] += ps;
        }

        // cross-lane dependency through Pw: drain LDS, fence the scheduler
        asm volatile("s_waitcnt lgkmcnt(0)" ::: "memory");
        __builtin_amdgcn_sched_barrier(0);

        // ---- PV: acc[16 i][256 c] += P[16 i][64 j] * V[64 j][256 c] ----
        f16x8 pa[2];
#pragma unroll
        for (int kc = 0; kc < 2; ++kc) {
            int slot = (kc * 4 + l4) ^ (l15 & 7);
            pa[kc] = *(const f16x8*)&Pw[l15 * 64 + slot * 8];
        }
        const _Float16* vb0 = Vt + (size_t)b * CDIM * NTOK + j0;
#pragma unroll
        for (int ct = 0; ct < 16; ++ct) {
#pragma unroll
            for (int kc = 0; kc < 2; ++kc) {
                f16x8 vb = *(const f16x8*)(vb0 + (size_t)(ct * 16 + l15) * NTOK
                                           + kc * 32 + l4 * 8);
                acc[ct] = MFMA16(pa[kc], vb, acc[ct]);
            }
        }
    }

    // ---- epilogue: write unnormalized partials ----
    float* pb = pacc + ((size_t)z * BATCH + b) * NTOK * CDIM;
#pragma unroll
    for (int reg = 0; reg < 4; ++reg) {
        int n = row0 + 4 * l4 + reg;
        float* prow = pb + (size_t)n * CDIM;
#pragma unroll
        for (int ct = 0; ct < 16; ++ct) prow[ct * 16 + l15] = acc[ct][reg];
        if (l15 == 0)
            pml[((size_t)z * BATCH + b) * NTOK + n] = make_float2(m[reg], l[reg]);
    }
}

// ---------------------------------------------------------------------------
// Merge: out[b][c][n] = (sum_s exp(m_s-M) acc_s[n][c]) / (sum_s exp(m_s-M) l_s)
// Block: (n-tile of 64) x batch. LDS transpose for coalesced [B,C,N] writes.
// ---------------------------------------------------------------------------
template <int SEG>
__global__ __launch_bounds__(256) void merge_kernel(
    const float* __restrict__ pacc, const float2* __restrict__ pml,
    float* __restrict__ out)
{
    const int tid = threadIdx.x;
    const int n0 = blockIdx.x * 64;
    const int b  = blockIdx.y;

    __shared__ float wgt[SEG][64];
    __shared__ float dinv[64];
    __shared__ float T[64][68];

    if (tid < 64) {
        int n = n0 + tid;
        float ms[SEG], ls[SEG];
#pragma unroll
        for (int s = 0; s < SEG; ++s) {
            float2 v = pml[((size_t)s * BATCH + b) * NTOK + n];
            ms[s] = v.x; ls[s] = v.y;
        }
        float M = ms[0];
#pragma unroll
        for (int s = 1; s < SEG; ++s) M = fmaxf(M, ms[s]);
        float den = 0.f;
#pragma unroll
        for (int s = 0; s < SEG; ++s) {
            float g = __expf(ms[s] - M);
            wgt[s][tid] = g;
            den += ls[s] * g;
        }
        dinv[tid] = 1.f / den;
    }
    __syncthreads();

    for (int cc = 0; cc < 4; ++cc) {
        const int nl = tid >> 2, cg = (tid & 3) * 16;
        float4 a0 = {0,0,0,0}, a1 = {0,0,0,0}, a2 = {0,0,0,0}, a3 = {0,0,0,0};
#pragma unroll
        for (int s = 0; s < SEG; ++s) {
            const float* p = pacc + (((size_t)s * BATCH + b) * NTOK + n0 + nl) * CDIM
                             + cc * 64 + cg;
            float g = wgt[s][nl];
            float4 v0 = *(const float4*)&p[0];
            float4 v1 = *(const float4*)&p[4];
            float4 v2 = *(const float4*)&p[8];
            float4 v3 = *(const float4*)&p[12];
            a0.x += g * v0.x; a0.y += g * v0.y; a0.z += g * v0.z; a0.w += g * v0.w;
            a1.x += g * v1.x; a1.y += g * v1.y; a1.z += g * v1.z; a1.w += g * v1.w;
            a2.x += g * v2.x; a2.y += g * v2.y; a2.z += g * v2.z; a2.w += g * v2.w;
            a3.x += g * v3.x; a3.y += g * v3.y; a3.z += g * v3.z; a3.w += g * v3.w;
        }
        float di = dinv[nl];
        a0.x *= di; a0.y *= di; a0.z *= di; a0.w *= di;
        a1.x *= di; a1.y *= di; a1.z *= di; a1.w *= di;
        a2.x *= di; a2.y *= di; a2.z *= di; a2.w *= di;
        a3.x *= di; a3.y *= di; a3.z *= di; a3.w *= di;
        *(float4*)&T[nl][cg + 0]  = a0;
        *(float4*)&T[nl][cg + 4]  = a1;
        *(float4*)&T[nl][cg + 8]  = a2;
        *(float4*)&T[nl][cg + 12] = a3;
        __syncthreads();

        const int cl = tid >> 2, nb2 = (tid & 3) * 16;
        float* ob = out + ((size_t)b * CDIM + cc * 64 + cl) * NTOK + n0 + nb2;
#pragma unroll
        for (int u = 0; u < 4; ++u) {
            float4 v = { T[nb2 + u * 4 + 0][cl], T[nb2 + u * 4 + 1][cl],
                         T[nb2 + u * 4 + 2][cl], T[nb2 + u * 4 + 3][cl] };
            *(float4*)&ob[u * 4] = v;
        }
        __syncthreads();
    }
}

// ---------------------------------------------------------------------------
extern "C" void kernel_launch(void* const* d_in, const int* in_sizes, int n_in,
                              void* d_out, int out_size, void* d_ws, size_t ws_size,
                              hipStream_t stream)
{
    const float* x1 = (const float*)d_in[0];
    const float* x2 = (const float*)d_in[1];
    const float* Wq = (const float*)d_in[2];
    const float* bq = (const float*)d_in[3];
    const float* Wk = (const float*)d_in[4];
    const float* bk = (const float*)d_in[5];
    const float* Wv = (const float*)d_in[6];
    const float* bv = (const float*)d_in[7];
    float* out = (float*)d_out;

    const size_t plane = (size_t)BATCH * NTOK * CDIM;   // 4,718,592
    _Float16* ws16 = (_Float16*)d_ws;
    _Float16* Q  = ws16;
    _Float16* K  = ws16 + plane;
    _Float16* Vt = ws16 + 2 * plane;
    const size_t qkv_bytes = 3 * plane * sizeof(_Float16);  // 28,311,552

    auto need = [&](size_t S) {
        return qkv_bytes + S * plane * 4 + S * (size_t)BATCH * NTOK * 8;
    };
    const int SEG = (ws_size >= need(4)) ? 4 : (ws_size >= need(2)) ? 2 : 1;

    float*  pacc = (float*)((char*)d_ws + qkv_bytes);
    float2* pml  = (float2*)((char*)d_ws + qkv_bytes + (size_t)SEG * plane * 4);

    dim3 pgrid(NTOK / 64, 3, BATCH);
    proj_kernel<<<pgrid, dim3(256), 0, stream>>>(x1, x2, Wq, bq, Wk, bk, Wv, bv,
                                                 Q, K, Vt);

    const int nb = 36 * BATCH * SEG;
    if (SEG == 4) {
        attn_fa<4><<<dim3(nb), dim3(256), 0, stream>>>(Q, K, Vt, pacc, pml);
        merge_kernel<4><<<dim3(36, BATCH), dim3(256), 0, stream>>>(pacc, pml, out);
    } else if (SEG == 2) {
        attn_fa<2><<<dim3(nb), dim3(256), 0, stream>>>(Q, K, Vt, pacc, pml);
        merge_kernel<2><<<dim3(36, BATCH), dim3(256), 0, stream>>>(pacc, pml, out);
    } else {
        attn_fa<1><<<dim3(nb), dim3(256), 0, stream>>>(Q, K, Vt, pacc, pml);
        merge_kernel<1><<<dim3(36, BATCH), dim3(256), 0, stream>>>(pacc, pml, out);
    }
}

// Round 4
// 381.760 us; speedup vs baseline: 1.2296x; 1.2296x over previous
//
#include <hip/hip_runtime.h>
#include <cfloat>
#include <cstddef>
#include <cstdint>

#define BATCH 8
#define CDIM  256
#define NTOK  2304   // 48*48

typedef float    f32x4 __attribute__((ext_vector_type(4)));
typedef _Float16 f16x8 __attribute__((ext_vector_type(8)));
typedef _Float16 f16x4 __attribute__((ext_vector_type(4)));

#define MFMA16(a, b, c) __builtin_amdgcn_mfma_f32_16x16x32_f16(a, b, c, 0, 0, 0)

__device__ __forceinline__ void gl_lds16(const void* g, void* l) {
    __builtin_amdgcn_global_load_lds(
        (const __attribute__((address_space(1))) void*)g,
        (__attribute__((address_space(3))) void*)l, 16, 0, 0);
}

// ---------------------------------------------------------------------------
// Projection (fp32 math, fp16 store), o-tile = 256 x 64 n.  (unchanged, verified)
// mode 0: Q from x1 -> [B,N,C]; mode 1: K from x2 -> [B,N,C];
// mode 2: V from x2 -> [B,C,N].
// ---------------------------------------------------------------------------
__global__ __launch_bounds__(256) void proj_kernel(
    const float* __restrict__ x1, const float* __restrict__ x2,
    const float* __restrict__ Wq, const float* __restrict__ bq,
    const float* __restrict__ Wk, const float* __restrict__ bk,
    const float* __restrict__ Wv, const float* __restrict__ bv,
    _Float16* __restrict__ Qo, _Float16* __restrict__ Ko, _Float16* __restrict__ Vo)
{
    const int tid = threadIdx.x;
    const int tx = tid & 15, ty = tid >> 4;
    const int n0   = blockIdx.x * 64;
    const int mode = blockIdx.y;
    const int b    = blockIdx.z;

    const float* X    = (mode == 0) ? x1 : x2;
    const float* W    = (mode == 0) ? Wq : (mode == 1) ? Wk : Wv;
    const float* bias = (mode == 0) ? bq : (mode == 1) ? bk : bv;
    _Float16*    OUT  = (mode == 0) ? Qo : (mode == 1) ? Ko : Vo;

    __shared__ float Xs[16][64];
    __shared__ float Ws[16][260];

    float acc[4][4][4];
#pragma unroll
    for (int t = 0; t < 4; ++t)
#pragma unroll
        for (int u = 0; u < 4; ++u)
#pragma unroll
            for (int n = 0; n < 4; ++n) acc[t][u][n] = 0.f;

    for (int c0 = 0; c0 < CDIM; c0 += 16) {
        __syncthreads();
        {
            float4 xv = *(const float4*)&X[(size_t)(b * CDIM + c0 + (tid >> 4)) * NTOK
                                           + n0 + (tid & 15) * 4];
            *(float4*)&Xs[tid >> 4][(tid & 15) * 4] = xv;
        }
#pragma unroll
        for (int u = 0; u < 4; ++u) {
            float4 wv = *(const float4*)&W[(size_t)tid * CDIM + c0 + u * 4];
            Ws[u * 4 + 0][tid] = wv.x;
            Ws[u * 4 + 1][tid] = wv.y;
            Ws[u * 4 + 2][tid] = wv.z;
            Ws[u * 4 + 3][tid] = wv.w;
        }
        __syncthreads();
#pragma unroll
        for (int kc = 0; kc < 16; ++kc) {
            float4 xv = *(const float4*)&Xs[kc][tx * 4];
#pragma unroll
            for (int t = 0; t < 4; ++t) {
                float4 wv = *(const float4*)&Ws[kc][ty * 4 + t * 64];
                acc[t][0][0] = fmaf(wv.x, xv.x, acc[t][0][0]);
                acc[t][0][1] = fmaf(wv.x, xv.y, acc[t][0][1]);
                acc[t][0][2] = fmaf(wv.x, xv.z, acc[t][0][2]);
                acc[t][0][3] = fmaf(wv.x, xv.w, acc[t][0][3]);
                acc[t][1][0] = fmaf(wv.y, xv.x, acc[t][1][0]);
                acc[t][1][1] = fmaf(wv.y, xv.y, acc[t][1][1]);
                acc[t][1][2] = fmaf(wv.y, xv.z, acc[t][1][2]);
                acc[t][1][3] = fmaf(wv.y, xv.w, acc[t][1][3]);
                acc[t][2][0] = fmaf(wv.z, xv.x, acc[t][2][0]);
                acc[t][2][1] = fmaf(wv.z, xv.y, acc[t][2][1]);
                acc[t][2][2] = fmaf(wv.z, xv.z, acc[t][2][2]);
                acc[t][2][3] = fmaf(wv.z, xv.w, acc[t][2][3]);
                acc[t][3][0] = fmaf(wv.w, xv.x, acc[t][3][0]);
                acc[t][3][1] = fmaf(wv.w, xv.y, acc[t][3][1]);
                acc[t][3][2] = fmaf(wv.w, xv.z, acc[t][3][2]);
                acc[t][3][3] = fmaf(wv.w, xv.w, acc[t][3][3]);
            }
        }
    }

    if (mode <= 1) {
#pragma unroll
        for (int t = 0; t < 4; ++t) {
            float4 bb = *(const float4*)&bias[t * 64 + ty * 4];
#pragma unroll
            for (int n = 0; n < 4; ++n) {
                f16x4 v = { (_Float16)(acc[t][0][n] + bb.x),
                            (_Float16)(acc[t][1][n] + bb.y),
                            (_Float16)(acc[t][2][n] + bb.z),
                            (_Float16)(acc[t][3][n] + bb.w) };
                *(f16x4*)&OUT[(size_t)(b * NTOK + n0 + tx * 4 + n) * CDIM
                              + t * 64 + ty * 4] = v;
            }
        }
    } else {
#pragma unroll
        for (int t = 0; t < 4; ++t) {
            float4 bb = *(const float4*)&bias[t * 64 + ty * 4];
#pragma unroll
            for (int u = 0; u < 4; ++u) {
                float bu = (u == 0) ? bb.x : (u == 1) ? bb.y : (u == 2) ? bb.z : bb.w;
                f16x4 v = { (_Float16)(acc[t][u][0] + bu),
                            (_Float16)(acc[t][u][1] + bu),
                            (_Float16)(acc[t][u][2] + bu),
                            (_Float16)(acc[t][u][3] + bu) };
                *(f16x4*)&OUT[(size_t)(b * CDIM + t * 64 + ty * 4 + u) * NTOK
                              + n0 + tx * 4] = v;
            }
        }
    }
}

// ---------------------------------------------------------------------------
// Split-KV MFMA flash attention, LDS-staged K/V.
// Block = 8 waves x 16 q-rows = 128 q-rows. KVBLK = 64.
// LDS: Kl[64][256] f16 (32KB, rows 512B, chunk16 ^= row&7)
//      Vl[256][64] f16 (32KB, rows 128B, chunk16 ^= row&7)
//      Pl[8][16][64] f16 (16KB, wave-private slices)   total 80KB -> 2 blk/CU.
// Staging: global_load_lds width 16, linear LDS dest, pre-swizzled global src.
// pacc: per-segment NORMALIZED output, fp16 [SEG][B][N][C]; pml (m,l) f32.
// Fragment conventions (HW-verified rounds 2/3):
//   A: row=lane&15, k=(lane>>4)*8+e ; B: col=lane&15, k=(lane>>4)*8+e
//   D: col=lane&15, row=(lane>>4)*4+reg
// ---------------------------------------------------------------------------
template <int SEG>
__global__ __launch_bounds__(512, 4) void attn_fa(
    const _Float16* __restrict__ Q, const _Float16* __restrict__ K,
    const _Float16* __restrict__ Vt, _Float16* __restrict__ pacc,
    float2* __restrict__ pml)
{
    const int tid  = threadIdx.x;
    const int lane = tid & 63;
    const int w    = tid >> 6;
    const int l15  = lane & 15, l4 = lane >> 4;

    // bijective XCD-chunked swizzle (grid % 8 == 0)
    const int nb  = 18 * BATCH * SEG, cpx = nb / 8;
    const int bid = blockIdx.x;
    const int swz = (bid & 7) * cpx + (bid >> 3);
    const int x = swz % 18;
    const int b = (swz / 18) & 7;
    const int z = swz / 144;

    const int row0  = x * 128 + w * 16;
    const int jbase = z * (NTOK / SEG);

    __shared__ __align__(16) _Float16 Kl[64 * 256];
    __shared__ __align__(16) _Float16 Vl[256 * 64];
    __shared__ __align__(16) _Float16 Pl[8][16 * 64];
    _Float16* Pw = Pl[w];

    // Q fragments: 16 rows x 256 c
    f16x8 qa[8];
    {
        const _Float16* qb = Q + ((size_t)b * NTOK + row0 + l15) * CDIM + l4 * 8;
#pragma unroll
        for (int kk = 0; kk < 8; ++kk) qa[kk] = *(const f16x8*)(qb + kk * 32);
    }

    f32x4 acc[16];
#pragma unroll
    for (int ct = 0; ct < 16; ++ct) acc[ct] = (f32x4){0.f, 0.f, 0.f, 0.f};
    float m[4] = {-FLT_MAX, -FLT_MAX, -FLT_MAX, -FLT_MAX};
    float l[4] = {0.f, 0.f, 0.f, 0.f};

    const size_t kbb = (size_t)b * NTOK;
    const size_t vbb = (size_t)b * CDIM * NTOK;

    for (int jt = 0; jt < NTOK / SEG / 64; ++jt) {
        const int j0 = jbase + jt * 64;

        __syncthreads();   // previous tile fully consumed by all waves

        // ---- stage K tile [64 j][256 c]: instr i covers rows 2i,2i+1 ----
#pragma unroll
        for (int t = 0; t < 4; ++t) {
            int i = w * 4 + t;
            int krow = 2 * i + (lane >> 5);
            int chunk = lane & 31;
            const _Float16* src =
                K + (kbb + j0 + krow) * CDIM + ((chunk ^ (krow & 7)) * 8);
            gl_lds16(src, (char*)Kl + i * 1024);
        }
        // ---- stage V tile [256 c][64 j]: instr i covers rows 8i..8i+7 ----
#pragma unroll
        for (int t = 0; t < 4; ++t) {
            int i = w * 4 + t;
            int vrow = 8 * i + (lane >> 3);
            int chunk = lane & 7;
            const _Float16* src =
                Vt + vbb + (size_t)vrow * NTOK + j0 + ((chunk ^ (vrow & 7)) * 8);
            gl_lds16(src, (char*)Vl + i * 1024);
        }
        __syncthreads();   // compiler drains vmcnt(0) before s_barrier

        // ---- QK^T: S[16 i][64 j] from LDS ----
        f32x4 s[4];
#pragma unroll
        for (int nt = 0; nt < 4; ++nt) {
            const char* kb = (const char*)Kl + (nt * 16 + l15) * 512;
            f32x4 sv = (f32x4){0.f, 0.f, 0.f, 0.f};
#pragma unroll
            for (int kk = 0; kk < 8; ++kk) {
                f16x8 kf = *(const f16x8*)(kb + (((kk * 4 + l4) ^ (l15 & 7)) * 16));
                sv = MFMA16(qa[kk], kf, sv);
            }
            s[nt] = sv;
        }

        // ---- online softmax (rows i = 4*l4 + reg), defer-max THR=8 ----
#pragma unroll
        for (int reg = 0; reg < 4; ++reg) {
            float pm = fmaxf(fmaxf(s[0][reg], s[1][reg]),
                             fmaxf(s[2][reg], s[3][reg]));
            pm = fmaxf(pm, __shfl_xor(pm, 1));
            pm = fmaxf(pm, __shfl_xor(pm, 2));
            pm = fmaxf(pm, __shfl_xor(pm, 4));
            pm = fmaxf(pm, __shfl_xor(pm, 8));
            if (pm > m[reg] + 8.f) {
                float sc = __expf(m[reg] - pm);
                m[reg] = pm;
                l[reg] *= sc;
#pragma unroll
                for (int ct = 0; ct < 16; ++ct) acc[ct][reg] *= sc;
            }
            float ps = 0.f;
            const int r = 4 * l4 + reg;
#pragma unroll
            for (int nt = 0; nt < 4; ++nt) {
                float p = __expf(s[nt][reg] - m[reg]);
                ps += p;
                int j = nt * 16 + l15;
                Pw[r * 64 + ((j >> 3) ^ (r & 7)) * 8 + (j & 7)] = (_Float16)p;
            }
            ps += __shfl_xor(ps, 1);
            ps += __shfl_xor(ps, 2);
            ps += __shfl_xor(ps, 4);
            ps += __shfl_xor(ps, 8);
            l[reg] += ps;
        }

        // cross-lane dependency through Pw (wave-private): drain + fence
        asm volatile("s_waitcnt lgkmcnt(0)" ::: "memory");
        __builtin_amdgcn_sched_barrier(0);

        // ---- PV: acc[16 i][256 c] += P[16 i][64 j] * V[64 j][256 c] ----
        f16x8 pa[2];
#pragma unroll
        for (int kc = 0; kc < 2; ++kc)
            pa[kc] = *(const f16x8*)((const char*)Pw + l15 * 128
                                     + (((kc * 4 + l4) ^ (l15 & 7)) * 16));
#pragma unroll
        for (int ct = 0; ct < 16; ++ct) {
            const char* vb0 = (const char*)Vl + (ct * 16 + l15) * 128;
#pragma unroll
            for (int kc = 0; kc < 2; ++kc) {
                f16x8 vb = *(const f16x8*)(vb0 + (((kc * 4 + l4) ^ (l15 & 7)) * 16));
                acc[ct] = MFMA16(pa[kc], vb, acc[ct]);
            }
        }
    }

    // ---- epilogue: per-segment normalized fp16 partials ----
    _Float16* pb = pacc + ((size_t)z * BATCH + b) * NTOK * CDIM;
#pragma unroll
    for (int reg = 0; reg < 4; ++reg) {
        int n = row0 + 4 * l4 + reg;
        float inv = 1.f / l[reg];
        _Float16* prow = pb + (size_t)n * CDIM;
#pragma unroll
        for (int ct = 0; ct < 16; ++ct)
            prow[ct * 16 + l15] = (_Float16)(acc[ct][reg] * inv);
        if (l15 == 0)
            pml[((size_t)z * BATCH + b) * NTOK + n] = make_float2(m[reg], l[reg]);
    }
}

// ---------------------------------------------------------------------------
// Merge: out[b][c][n] = sum_s w_s * ohat_s[n][c] / sum_s w_s,  w_s = l_s e^(m_s-M)
// ---------------------------------------------------------------------------
template <int SEG>
__global__ __launch_bounds__(256) void merge_kernel(
    const _Float16* __restrict__ pacc, const float2* __restrict__ pml,
    float* __restrict__ out)
{
    const int tid = threadIdx.x;
    const int n0 = blockIdx.x * 64;
    const int b  = blockIdx.y;

    __shared__ float wgt[SEG][64];
    __shared__ float dinv[64];
    __shared__ float T[64][68];

    if (tid < 64) {
        int n = n0 + tid;
        float ms[SEG], ls[SEG];
#pragma unroll
        for (int s = 0; s < SEG; ++s) {
            float2 v = pml[((size_t)s * BATCH + b) * NTOK + n];
            ms[s] = v.x; ls[s] = v.y;
        }
        float M = ms[0];
#pragma unroll
        for (int s = 1; s < SEG; ++s) M = fmaxf(M, ms[s]);
        float den = 0.f;
#pragma unroll
        for (int s = 0; s < SEG; ++s) {
            float g = ls[s] * __expf(ms[s] - M);
            wgt[s][tid] = g;
            den += g;
        }
        dinv[tid] = 1.f / den;
    }
    __syncthreads();

    for (int cc = 0; cc < 4; ++cc) {
        const int nl = tid >> 2, cg = (tid & 3) * 16;
        float a[16];
#pragma unroll
        for (int u = 0; u < 16; ++u) a[u] = 0.f;
#pragma unroll
        for (int s = 0; s < SEG; ++s) {
            const _Float16* p = pacc + (((size_t)s * BATCH + b) * NTOK + n0 + nl) * CDIM
                                + cc * 64 + cg;
            f16x8 v0 = ((const f16x8*)p)[0];
            f16x8 v1 = ((const f16x8*)p)[1];
            float g = wgt[s][nl];
#pragma unroll
            for (int u = 0; u < 8; ++u) {
                a[u]     += g * (float)v0[u];
                a[8 + u] += g * (float)v1[u];
            }
        }
        float di = dinv[nl];
#pragma unroll
        for (int u = 0; u < 16; ++u) T[nl][cg + u] = a[u] * di;
        __syncthreads();

        const int cl = tid >> 2, nb2 = (tid & 3) * 16;
        float* ob = out + ((size_t)b * CDIM + cc * 64 + cl) * NTOK + n0 + nb2;
#pragma unroll
        for (int u = 0; u < 4; ++u) {
            float4 v = { T[nb2 + u * 4 + 0][cl], T[nb2 + u * 4 + 1][cl],
                         T[nb2 + u * 4 + 2][cl], T[nb2 + u * 4 + 3][cl] };
            *(float4*)&ob[u * 4] = v;
        }
        __syncthreads();
    }
}

// ---------------------------------------------------------------------------
extern "C" void kernel_launch(void* const* d_in, const int* in_sizes, int n_in,
                              void* d_out, int out_size, void* d_ws, size_t ws_size,
                              hipStream_t stream)
{
    const float* x1 = (const float*)d_in[0];
    const float* x2 = (const float*)d_in[1];
    const float* Wq = (const float*)d_in[2];
    const float* bq = (const float*)d_in[3];
    const float* Wk = (const float*)d_in[4];
    const float* bk = (const float*)d_in[5];
    const float* Wv = (const float*)d_in[6];
    const float* bv = (const float*)d_in[7];
    float* out = (float*)d_out;

    const size_t plane = (size_t)BATCH * NTOK * CDIM;   // 4,718,592
    _Float16* ws16 = (_Float16*)d_ws;
    _Float16* Q  = ws16;
    _Float16* K  = ws16 + plane;
    _Float16* Vt = ws16 + 2 * plane;
    const size_t qkv_bytes = 3 * plane * sizeof(_Float16);

    auto need = [&](size_t S) {
        return qkv_bytes + S * plane * 2 + S * (size_t)BATCH * NTOK * 8;
    };
    const int SEG = (ws_size >= need(4)) ? 4 : (ws_size >= need(2)) ? 2 : 1;

    _Float16* pacc = (_Float16*)((char*)d_ws + qkv_bytes);
    float2*   pml  = (float2*)((char*)d_ws + qkv_bytes + (size_t)SEG * plane * 2);

    dim3 pgrid(NTOK / 64, 3, BATCH);
    proj_kernel<<<pgrid, dim3(256), 0, stream>>>(x1, x2, Wq, bq, Wk, bk, Wv, bv,
                                                 Q, K, Vt);

    const int nb = 18 * BATCH;
    if (SEG == 4) {
        attn_fa<4><<<dim3(nb * 4), dim3(512), 0, stream>>>(Q, K, Vt, pacc, pml);
        merge_kernel<4><<<dim3(36, BATCH), dim3(256), 0, stream>>>(pacc, pml, out);
    } else if (SEG == 2) {
        attn_fa<2><<<dim3(nb * 2), dim3(512), 0, stream>>>(Q, K, Vt, pacc, pml);
        merge_kernel<2><<<dim3(36, BATCH), dim3(256), 0, stream>>>(pacc, pml, out);
    } else {
        attn_fa<1><<<dim3(nb), dim3(512), 0, stream>>>(Q, K, Vt, pacc, pml);
        merge_kernel<1><<<dim3(36, BATCH), dim3(256), 0, stream>>>(pacc, pml, out);
    }
}

// Round 5
// 326.901 us; speedup vs baseline: 1.4359x; 1.1678x over previous
//
#include <hip/hip_runtime.h>
#include <cfloat>
#include <cstddef>
#include <cstdint>

#define BATCH 8
#define CDIM  256
#define NTOK  2304   // 48*48

typedef float    f32x4 __attribute__((ext_vector_type(4)));
typedef _Float16 f16x8 __attribute__((ext_vector_type(8)));
typedef _Float16 f16x4 __attribute__((ext_vector_type(4)));

#define MFMA16(a, b, c) __builtin_amdgcn_mfma_f32_16x16x32_f16(a, b, c, 0, 0, 0)

__device__ __forceinline__ void gl_lds16(const void* g, void* l) {
    __builtin_amdgcn_global_load_lds(
        (const __attribute__((address_space(1))) void*)g,
        (__attribute__((address_space(3))) void*)l, 16, 0, 0);
}

// ---------------------------------------------------------------------------
// cast_w: Wq|Wk|Wv fp32 -> Wh fp16 [3][256][256]
// ---------------------------------------------------------------------------
__global__ __launch_bounds__(256) void cast_w(
    const float* __restrict__ Wq, const float* __restrict__ Wk,
    const float* __restrict__ Wv, _Float16* __restrict__ Wh)
{
    int i = (blockIdx.x * 256 + threadIdx.x) * 4;   // grid 192 -> 196608 floats
    const float* src = (i < 65536) ? (Wq + i)
                     : (i < 131072) ? (Wk + (i - 65536)) : (Wv + (i - 131072));
    float4 v = *(const float4*)src;
    f16x4 h = { (_Float16)v.x, (_Float16)v.y, (_Float16)v.z, (_Float16)v.w };
    *(f16x4*)(Wh + i) = h;
}

// ---------------------------------------------------------------------------
// cast_x: x [B,C,N] fp32 -> Xt [B,N,C] fp16 (64x64 LDS tile transpose)
// grid (36 n-tiles, 4 c-tiles, 16 = b*2)
// ---------------------------------------------------------------------------
__global__ __launch_bounds__(256) void cast_x(
    const float* __restrict__ x1, const float* __restrict__ x2,
    _Float16* __restrict__ Xt1, _Float16* __restrict__ Xt2)
{
    const int tid = threadIdx.x;
    const int n0 = blockIdx.x * 64;
    const int c0 = blockIdx.y * 64;
    const int bz = blockIdx.z;
    const float* X   = (bz < 8) ? x1 : x2;
    _Float16*   Xt   = (bz < 8) ? Xt1 : Xt2;
    const int b = bz & 7;

    __shared__ _Float16 T[64][72];

    {
        const int cl = tid >> 2, nch = (tid & 3) * 16;
        const float* src = X + (size_t)(b * CDIM + c0 + cl) * NTOK + n0 + nch;
#pragma unroll
        for (int u = 0; u < 4; ++u) {
            float4 v = *(const float4*)(src + u * 4);
            T[cl][nch + u * 4 + 0] = (_Float16)v.x;
            T[cl][nch + u * 4 + 1] = (_Float16)v.y;
            T[cl][nch + u * 4 + 2] = (_Float16)v.z;
            T[cl][nch + u * 4 + 3] = (_Float16)v.w;
        }
    }
    __syncthreads();
    {
        const int nl = tid >> 2, cch = (tid & 3) * 16;
        _Float16* dst = Xt + (size_t)(b * NTOK + n0 + nl) * CDIM + c0 + cch;
        f16x8 o0, o1;
#pragma unroll
        for (int i = 0; i < 8; ++i) {
            o0[i] = T[cch + i][nl];
            o1[i] = T[cch + 8 + i][nl];
        }
        *(f16x8*)dst = o0;
        *(f16x8*)(dst + 8) = o1;
    }
}

// ---------------------------------------------------------------------------
// proj_mfma: OUT = Xt * W^T + b via MFMA.
// Block: [64 n][256 o] tile, 4 waves (wave w owns o-range w*64).
// LDS: Xl [64 n][256 c] 32KB (staged once), Wl [256 o][64 c] 32KB (per c-chunk).
// Swizzle: chunk16 ^= row&7 (round-4-verified pattern).
// mode 0: Q->[B,N,C]; 1: K->[B,N,C]; 2: V->[B,C,N]; LDS-transpose epilogues.
// ---------------------------------------------------------------------------
__global__ __launch_bounds__(256, 2) void proj_mfma(
    const _Float16* __restrict__ Xt1, const _Float16* __restrict__ Xt2,
    const _Float16* __restrict__ Wh,
    const float* __restrict__ bq, const float* __restrict__ bk,
    const float* __restrict__ bv,
    _Float16* __restrict__ Qo, _Float16* __restrict__ Ko, _Float16* __restrict__ Vo)
{
    const int tid  = threadIdx.x;
    const int lane = tid & 63;
    const int w    = tid >> 6;
    const int l15  = lane & 15, l4 = lane >> 4;
    const int n0   = blockIdx.x * 64;
    const int mode = blockIdx.y;
    const int b    = blockIdx.z;

    const _Float16* Xt = (mode == 0) ? Xt1 : Xt2;
    const _Float16* Wm = Wh + mode * 65536;
    const float* bias  = (mode == 0) ? bq : (mode == 1) ? bk : bv;
    _Float16* OUT      = (mode == 0) ? Qo : (mode == 1) ? Ko : Vo;

    __shared__ __align__(16) char sm[65536];
    _Float16* Xl = (_Float16*)sm;             // [64][256], rows 512B
    _Float16* Wl = (_Float16*)(sm + 32768);   // [256][64], rows 128B

    // stage Xl once (32 x gl_lds16, coalesced, pre-swizzled source)
#pragma unroll
    for (int t = 0; t < 8; ++t) {
        int i = w * 8 + t;
        int row = 2 * i + (lane >> 5);
        int ch  = lane & 31;
        gl_lds16(Xt + (size_t)(b * NTOK + n0 + row) * CDIM + ((ch ^ (row & 7)) * 8),
                 (char*)Xl + i * 1024);
    }

    float bias_o[4];
#pragma unroll
    for (int ot = 0; ot < 4; ++ot) bias_o[ot] = bias[w * 64 + ot * 16 + l15];

    f32x4 acc[16];
#pragma unroll
    for (int i = 0; i < 16; ++i) acc[i] = (f32x4){0.f, 0.f, 0.f, 0.f};

    for (int c0 = 0; c0 < CDIM; c0 += 64) {
        __syncthreads();   // Wl consumed by previous chunk
#pragma unroll
        for (int t = 0; t < 8; ++t) {
            int i = w * 8 + t;
            int row = 8 * i + (lane >> 3);
            int ch  = lane & 7;
            gl_lds16(Wm + (size_t)row * CDIM + c0 + ((ch ^ (row & 7)) * 8),
                     (char*)Wl + i * 1024);
        }
        __syncthreads();   // vmcnt drained (Xl ready after first chunk too)

#pragma unroll
        for (int kk2 = 0; kk2 < 2; ++kk2) {
            f16x8 a[4], bf[4];
#pragma unroll
            for (int nt = 0; nt < 4; ++nt) {
                int row = nt * 16 + l15;
                int ch  = ((c0 >> 3) + kk2 * 4 + l4) ^ (row & 7);
                a[nt] = *(const f16x8*)((const char*)Xl + row * 512 + ch * 16);
            }
#pragma unroll
            for (int ot = 0; ot < 4; ++ot) {
                int row = w * 64 + ot * 16 + l15;
                int ch  = (kk2 * 4 + l4) ^ (row & 7);
                bf[ot] = *(const f16x8*)((const char*)Wl + row * 128 + ch * 16);
            }
#pragma unroll
            for (int nt = 0; nt < 4; ++nt)
#pragma unroll
                for (int ot = 0; ot < 4; ++ot)
                    acc[nt * 4 + ot] = MFMA16(a[nt], bf[ot], acc[nt * 4 + ot]);
        }
    }

    __syncthreads();   // done with Xl/Wl; reuse sm for epilogue

    if (mode <= 1) {
        // D[n][o] packed [64][256]; then linear 32KB copy (rows of [B,N,C])
        _Float16* Dl = (_Float16*)sm;
#pragma unroll
        for (int nt = 0; nt < 4; ++nt)
#pragma unroll
            for (int ot = 0; ot < 4; ++ot)
#pragma unroll
                for (int reg = 0; reg < 4; ++reg)
                    Dl[(nt * 16 + 4 * l4 + reg) * 256 + w * 64 + ot * 16 + l15] =
                        (_Float16)(acc[nt * 4 + ot][reg] + bias_o[ot]);
        __syncthreads();
        char* dst = (char*)(OUT + ((size_t)b * NTOK + n0) * CDIM);
#pragma unroll
        for (int u = 0; u < 8; ++u) {
            f16x8 v = *(const f16x8*)((const char*)Dl + u * 4096 + tid * 16);
            *(f16x8*)(dst + u * 4096 + tid * 16) = v;
        }
    } else {
        // D^T [o][n] padded rows 80 f16 (160B, b128-aligned); 8-rows/instr writes
        _Float16* Dlv = (_Float16*)sm;   // [256][80] = 40KB
#pragma unroll
        for (int nt = 0; nt < 4; ++nt)
#pragma unroll
            for (int ot = 0; ot < 4; ++ot)
#pragma unroll
                for (int reg = 0; reg < 4; ++reg)
                    Dlv[(w * 64 + ot * 16 + l15) * 80 + nt * 16 + 4 * l4 + reg] =
                        (_Float16)(acc[nt * 4 + ot][reg] + bias_o[ot]);
        __syncthreads();
#pragma unroll
        for (int t = 0; t < 8; ++t) {
            int ro = (w * 8 + t) * 8 + (lane >> 3);
            f16x8 v = *(const f16x8*)((const char*)Dlv + ro * 160 + (lane & 7) * 16);
            *(f16x8*)(OUT + ((size_t)b * CDIM + ro) * NTOK + n0 + (lane & 7) * 8) = v;
        }
    }
}

// ---------------------------------------------------------------------------
// Split-KV MFMA flash attention, LDS-staged K/V (round-4 main loop, verified).
// NEW: nontemporal Q loads; epilogue staged through LDS -> linear nontemporal
// 16B/lane pacc stores (no partial-line RMW, no L2 pollution).
// ---------------------------------------------------------------------------
template <int SEG>
__global__ __launch_bounds__(512, 4) void attn_fa(
    const _Float16* __restrict__ Q, const _Float16* __restrict__ K,
    const _Float16* __restrict__ Vt, _Float16* __restrict__ pacc,
    float2* __restrict__ pml)
{
    const int tid  = threadIdx.x;
    const int lane = tid & 63;
    const int w    = tid >> 6;
    const int l15  = lane & 15, l4 = lane >> 4;

    // bijective XCD-chunked swizzle (grid % 8 == 0)
    const int nb  = 18 * BATCH * SEG, cpx = nb / 8;
    const int bid = blockIdx.x;
    const int swz = (bid & 7) * cpx + (bid >> 3);
    const int x = swz % 18;
    const int b = (swz / 18) & 7;
    const int z = swz / 144;

    const int row0  = x * 128 + w * 16;
    const int jbase = z * (NTOK / SEG);

    __shared__ __align__(16) char smem[81920];
    _Float16* Kl = (_Float16*)smem;                       // [64][256] 32KB
    _Float16* Vl = (_Float16*)(smem + 32768);             // [256][64] 32KB
    _Float16* Pw = (_Float16*)(smem + 65536 + w * 2048);  // wave-private 2KB

    // Q fragments: 16 rows x 256 c (nontemporal: single-use stream)
    f16x8 qa[8];
    {
        const _Float16* qb = Q + ((size_t)b * NTOK + row0 + l15) * CDIM + l4 * 8;
#pragma unroll
        for (int kk = 0; kk < 8; ++kk)
            qa[kk] = __builtin_nontemporal_load((const f16x8*)(qb + kk * 32));
    }

    f32x4 acc[16];
#pragma unroll
    for (int ct = 0; ct < 16; ++ct) acc[ct] = (f32x4){0.f, 0.f, 0.f, 0.f};
    float m[4] = {-FLT_MAX, -FLT_MAX, -FLT_MAX, -FLT_MAX};
    float l[4] = {0.f, 0.f, 0.f, 0.f};

    const size_t kbb = (size_t)b * NTOK;
    const size_t vbb = (size_t)b * CDIM * NTOK;

    for (int jt = 0; jt < NTOK / SEG / 64; ++jt) {
        const int j0 = jbase + jt * 64;

        __syncthreads();

        // stage K tile [64 j][256 c]
#pragma unroll
        for (int t = 0; t < 4; ++t) {
            int i = w * 4 + t;
            int krow = 2 * i + (lane >> 5);
            int chunk = lane & 31;
            const _Float16* src =
                K + (kbb + j0 + krow) * CDIM + ((chunk ^ (krow & 7)) * 8);
            gl_lds16(src, (char*)Kl + i * 1024);
        }
        // stage V tile [256 c][64 j]
#pragma unroll
        for (int t = 0; t < 4; ++t) {
            int i = w * 4 + t;
            int vrow = 8 * i + (lane >> 3);
            int chunk = lane & 7;
            const _Float16* src =
                Vt + vbb + (size_t)vrow * NTOK + j0 + ((chunk ^ (vrow & 7)) * 8);
            gl_lds16(src, (char*)Vl + i * 1024);
        }
        __syncthreads();

        // QK^T
        f32x4 s[4];
#pragma unroll
        for (int nt = 0; nt < 4; ++nt) {
            const char* kb = (const char*)Kl + (nt * 16 + l15) * 512;
            f32x4 sv = (f32x4){0.f, 0.f, 0.f, 0.f};
#pragma unroll
            for (int kk = 0; kk < 8; ++kk) {
                f16x8 kf = *(const f16x8*)(kb + (((kk * 4 + l4) ^ (l15 & 7)) * 16));
                sv = MFMA16(qa[kk], kf, sv);
            }
            s[nt] = sv;
        }

        // online softmax, defer-max THR=8
#pragma unroll
        for (int reg = 0; reg < 4; ++reg) {
            float pm = fmaxf(fmaxf(s[0][reg], s[1][reg]),
                             fmaxf(s[2][reg], s[3][reg]));
            pm = fmaxf(pm, __shfl_xor(pm, 1));
            pm = fmaxf(pm, __shfl_xor(pm, 2));
            pm = fmaxf(pm, __shfl_xor(pm, 4));
            pm = fmaxf(pm, __shfl_xor(pm, 8));
            if (pm > m[reg] + 8.f) {
                float sc = __expf(m[reg] - pm);
                m[reg] = pm;
                l[reg] *= sc;
#pragma unroll
                for (int ct = 0; ct < 16; ++ct) acc[ct][reg] *= sc;
            }
            float ps = 0.f;
            const int r = 4 * l4 + reg;
#pragma unroll
            for (int nt = 0; nt < 4; ++nt) {
                float p = __expf(s[nt][reg] - m[reg]);
                ps += p;
                int j = nt * 16 + l15;
                Pw[r * 64 + ((j >> 3) ^ (r & 7)) * 8 + (j & 7)] = (_Float16)p;
            }
            ps += __shfl_xor(ps, 1);
            ps += __shfl_xor(ps, 2);
            ps += __shfl_xor(ps, 4);
            ps += __shfl_xor(ps, 8);
            l[reg] += ps;
        }

        asm volatile("s_waitcnt lgkmcnt(0)" ::: "memory");
        __builtin_amdgcn_sched_barrier(0);

        // PV
        f16x8 pa[2];
#pragma unroll
        for (int kc = 0; kc < 2; ++kc)
            pa[kc] = *(const f16x8*)((const char*)Pw + l15 * 128
                                     + (((kc * 4 + l4) ^ (l15 & 7)) * 16));
#pragma unroll
        for (int ct = 0; ct < 16; ++ct) {
            const char* vb0 = (const char*)Vl + (ct * 16 + l15) * 128;
#pragma unroll
            for (int kc = 0; kc < 2; ++kc) {
                f16x8 vb = *(const f16x8*)(vb0 + (((kc * 4 + l4) ^ (l15 & 7)) * 16));
                acc[ct] = MFMA16(pa[kc], vb, acc[ct]);
            }
        }
    }

    // ---- epilogue: LDS-staged, linear nontemporal pacc stores ----
    __syncthreads();   // all waves done with Kl/Vl
    _Float16* stg = (_Float16*)(smem + w * 8192);   // wave-private 8KB
#pragma unroll
    for (int reg = 0; reg < 4; ++reg) {
        float inv = 1.f / l[reg];
        int r = 4 * l4 + reg;
#pragma unroll
        for (int ct = 0; ct < 16; ++ct)
            stg[r * 256 + ct * 16 + l15] = (_Float16)(acc[ct][reg] * inv);
        if (l15 == 0)
            pml[((size_t)z * BATCH + b) * NTOK + row0 + r] = make_float2(m[reg], l[reg]);
    }
    asm volatile("s_waitcnt lgkmcnt(0)" ::: "memory");
    __builtin_amdgcn_sched_barrier(0);
    {
        const char* stgc = (const char*)stg;
        char* dst = (char*)(pacc + ((size_t)z * BATCH + b) * NTOK * CDIM
                            + (size_t)row0 * CDIM);
#pragma unroll
        for (int u = 0; u < 8; ++u) {
            f16x8 v = *(const f16x8*)(stgc + u * 1024 + lane * 16);
            __builtin_nontemporal_store(v, (f16x8*)(dst + u * 1024 + lane * 16));
        }
    }
}

// ---------------------------------------------------------------------------
// Merge (unchanged from round 4, verified)
// ---------------------------------------------------------------------------
template <int SEG>
__global__ __launch_bounds__(256) void merge_kernel(
    const _Float16* __restrict__ pacc, const float2* __restrict__ pml,
    float* __restrict__ out)
{
    const int tid = threadIdx.x;
    const int n0 = blockIdx.x * 64;
    const int b  = blockIdx.y;

    __shared__ float wgt[SEG][64];
    __shared__ float dinv[64];
    __shared__ float T[64][68];

    if (tid < 64) {
        int n = n0 + tid;
        float ms[SEG], ls[SEG];
#pragma unroll
        for (int s = 0; s < SEG; ++s) {
            float2 v = pml[((size_t)s * BATCH + b) * NTOK + n];
            ms[s] = v.x; ls[s] = v.y;
        }
        float M = ms[0];
#pragma unroll
        for (int s = 1; s < SEG; ++s) M = fmaxf(M, ms[s]);
        float den = 0.f;
#pragma unroll
        for (int s = 0; s < SEG; ++s) {
            float g = ls[s] * __expf(ms[s] - M);
            wgt[s][tid] = g;
            den += g;
        }
        dinv[tid] = 1.f / den;
    }
    __syncthreads();

    for (int cc = 0; cc < 4; ++cc) {
        const int nl = tid >> 2, cg = (tid & 3) * 16;
        float a[16];
#pragma unroll
        for (int u = 0; u < 16; ++u) a[u] = 0.f;
#pragma unroll
        for (int s = 0; s < SEG; ++s) {
            const _Float16* p = pacc + (((size_t)s * BATCH + b) * NTOK + n0 + nl) * CDIM
                                + cc * 64 + cg;
            f16x8 v0 = ((const f16x8*)p)[0];
            f16x8 v1 = ((const f16x8*)p)[1];
            float g = wgt[s][nl];
#pragma unroll
            for (int u = 0; u < 8; ++u) {
                a[u]     += g * (float)v0[u];
                a[8 + u] += g * (float)v1[u];
            }
        }
        float di = dinv[nl];
#pragma unroll
        for (int u = 0; u < 16; ++u) T[nl][cg + u] = a[u] * di;
        __syncthreads();

        const int cl = tid >> 2, nb2 = (tid & 3) * 16;
        float* ob = out + ((size_t)b * CDIM + cc * 64 + cl) * NTOK + n0 + nb2;
#pragma unroll
        for (int u = 0; u < 4; ++u) {
            float4 v = { T[nb2 + u * 4 + 0][cl], T[nb2 + u * 4 + 1][cl],
                         T[nb2 + u * 4 + 2][cl], T[nb2 + u * 4 + 3][cl] };
            *(float4*)&ob[u * 4] = v;
        }
        __syncthreads();
    }
}

// ---------------------------------------------------------------------------
extern "C" void kernel_launch(void* const* d_in, const int* in_sizes, int n_in,
                              void* d_out, int out_size, void* d_ws, size_t ws_size,
                              hipStream_t stream)
{
    const float* x1 = (const float*)d_in[0];
    const float* x2 = (const float*)d_in[1];
    const float* Wq = (const float*)d_in[2];
    const float* bq = (const float*)d_in[3];
    const float* Wk = (const float*)d_in[4];
    const float* bk = (const float*)d_in[5];
    const float* Wv = (const float*)d_in[6];
    const float* bv = (const float*)d_in[7];
    float* out = (float*)d_out;

    const size_t plane = (size_t)BATCH * NTOK * CDIM;   // 4,718,592
    _Float16* ws16 = (_Float16*)d_ws;
    _Float16* Q   = ws16;
    _Float16* K   = ws16 + plane;
    _Float16* Vt  = ws16 + 2 * plane;
    _Float16* Xt1 = ws16 + 3 * plane;
    _Float16* Xt2 = ws16 + 4 * plane;
    _Float16* Wh  = ws16 + 5 * plane;                 // 196608 elems
    const size_t fixed16 = 5 * plane + 196608;

    auto need = [&](size_t S) {
        return fixed16 * 2 + S * plane * 2 + S * (size_t)BATCH * NTOK * 8;
    };
    const int SEG = (ws_size >= need(4)) ? 4 : (ws_size >= need(2)) ? 2 : 1;

    _Float16* pacc = ws16 + fixed16;
    float2*   pml  = (float2*)((char*)d_ws + fixed16 * 2 + (size_t)SEG * plane * 2);

    cast_w<<<dim3(192), dim3(256), 0, stream>>>(Wq, Wk, Wv, Wh);
    cast_x<<<dim3(36, 4, 16), dim3(256), 0, stream>>>(x1, x2, Xt1, Xt2);
    proj_mfma<<<dim3(36, 3, BATCH), dim3(256), 0, stream>>>(
        Xt1, Xt2, Wh, bq, bk, bv, Q, K, Vt);

    const int nb = 18 * BATCH;
    if (SEG == 4) {
        attn_fa<4><<<dim3(nb * 4), dim3(512), 0, stream>>>(Q, K, Vt, pacc, pml);
        merge_kernel<4><<<dim3(36, BATCH), dim3(256), 0, stream>>>(pacc, pml, out);
    } else if (SEG == 2) {
        attn_fa<2><<<dim3(nb * 2), dim3(512), 0, stream>>>(Q, K, Vt, pacc, pml);
        merge_kernel<2><<<dim3(36, BATCH), dim3(256), 0, stream>>>(pacc, pml, out);
    } else {
        attn_fa<1><<<dim3(nb), dim3(512), 0, stream>>>(Q, K, Vt, pacc, pml);
        merge_kernel<1><<<dim3(36, BATCH), dim3(256), 0, stream>>>(pacc, pml, out);
    }
}

// Round 6
// 159.798 us; speedup vs baseline: 2.9374x; 2.0457x over previous
//
#include <hip/hip_runtime.h>
#include <cfloat>
#include <cstddef>
#include <cstdint>

#define BATCH 8
#define CDIM  256
#define NTOK  2304   // 48*48

typedef float    f32x4 __attribute__((ext_vector_type(4)));
typedef _Float16 f16x8 __attribute__((ext_vector_type(8)));
typedef _Float16 f16x4 __attribute__((ext_vector_type(4)));

#define MFMA16(a, b, c) __builtin_amdgcn_mfma_f32_16x16x32_f16(a, b, c, 0, 0, 0)

__device__ __forceinline__ void gl_lds16(const void* g, void* l) {
    __builtin_amdgcn_global_load_lds(
        (const __attribute__((address_space(1))) void*)g,
        (__attribute__((address_space(3))) void*)l, 16, 0, 0);
}

// ---------------------------------------------------------------------------
// cast_w: Wq|Wk|Wv fp32 -> Wh fp16 [3][256][256]   (unchanged, verified)
// ---------------------------------------------------------------------------
__global__ __launch_bounds__(256) void cast_w(
    const float* __restrict__ Wq, const float* __restrict__ Wk,
    const float* __restrict__ Wv, _Float16* __restrict__ Wh)
{
    int i = (blockIdx.x * 256 + threadIdx.x) * 4;
    const float* src = (i < 65536) ? (Wq + i)
                     : (i < 131072) ? (Wk + (i - 65536)) : (Wv + (i - 131072));
    float4 v = *(const float4*)src;
    f16x4 h = { (_Float16)v.x, (_Float16)v.y, (_Float16)v.z, (_Float16)v.w };
    *(f16x4*)(Wh + i) = h;
}

// ---------------------------------------------------------------------------
// cast_x: x [B,C,N] fp32 -> Xt [B,N,C] fp16   (unchanged, verified)
// ---------------------------------------------------------------------------
__global__ __launch_bounds__(256) void cast_x(
    const float* __restrict__ x1, const float* __restrict__ x2,
    _Float16* __restrict__ Xt1, _Float16* __restrict__ Xt2)
{
    const int tid = threadIdx.x;
    const int n0 = blockIdx.x * 64;
    const int c0 = blockIdx.y * 64;
    const int bz = blockIdx.z;
    const float* X   = (bz < 8) ? x1 : x2;
    _Float16*   Xt   = (bz < 8) ? Xt1 : Xt2;
    const int b = bz & 7;

    __shared__ _Float16 T[64][72];

    {
        const int cl = tid >> 2, nch = (tid & 3) * 16;
        const float* src = X + (size_t)(b * CDIM + c0 + cl) * NTOK + n0 + nch;
#pragma unroll
        for (int u = 0; u < 4; ++u) {
            float4 v = *(const float4*)(src + u * 4);
            T[cl][nch + u * 4 + 0] = (_Float16)v.x;
            T[cl][nch + u * 4 + 1] = (_Float16)v.y;
            T[cl][nch + u * 4 + 2] = (_Float16)v.z;
            T[cl][nch + u * 4 + 3] = (_Float16)v.w;
        }
    }
    __syncthreads();
    {
        const int nl = tid >> 2, cch = (tid & 3) * 16;
        _Float16* dst = Xt + (size_t)(b * NTOK + n0 + nl) * CDIM + c0 + cch;
        f16x8 o0, o1;
#pragma unroll
        for (int i = 0; i < 8; ++i) {
            o0[i] = T[cch + i][nl];
            o1[i] = T[cch + 8 + i][nl];
        }
        *(f16x8*)dst = o0;
        *(f16x8*)(dst + 8) = o1;
    }
}

// ---------------------------------------------------------------------------
// proj_mfma   (unchanged, verified)
// ---------------------------------------------------------------------------
__global__ __launch_bounds__(256, 2) void proj_mfma(
    const _Float16* __restrict__ Xt1, const _Float16* __restrict__ Xt2,
    const _Float16* __restrict__ Wh,
    const float* __restrict__ bq, const float* __restrict__ bk,
    const float* __restrict__ bv,
    _Float16* __restrict__ Qo, _Float16* __restrict__ Ko, _Float16* __restrict__ Vo)
{
    const int tid  = threadIdx.x;
    const int lane = tid & 63;
    const int w    = tid >> 6;
    const int l15  = lane & 15, l4 = lane >> 4;
    const int n0   = blockIdx.x * 64;
    const int mode = blockIdx.y;
    const int b    = blockIdx.z;

    const _Float16* Xt = (mode == 0) ? Xt1 : Xt2;
    const _Float16* Wm = Wh + mode * 65536;
    const float* bias  = (mode == 0) ? bq : (mode == 1) ? bk : bv;
    _Float16* OUT      = (mode == 0) ? Qo : (mode == 1) ? Ko : Vo;

    __shared__ __align__(16) char sm[65536];
    _Float16* Xl = (_Float16*)sm;
    _Float16* Wl = (_Float16*)(sm + 32768);

#pragma unroll
    for (int t = 0; t < 8; ++t) {
        int i = w * 8 + t;
        int row = 2 * i + (lane >> 5);
        int ch  = lane & 31;
        gl_lds16(Xt + (size_t)(b * NTOK + n0 + row) * CDIM + ((ch ^ (row & 7)) * 8),
                 (char*)Xl + i * 1024);
    }

    float bias_o[4];
#pragma unroll
    for (int ot = 0; ot < 4; ++ot) bias_o[ot] = bias[w * 64 + ot * 16 + l15];

    f32x4 acc[16];
#pragma unroll
    for (int i = 0; i < 16; ++i) acc[i] = (f32x4){0.f, 0.f, 0.f, 0.f};

    for (int c0 = 0; c0 < CDIM; c0 += 64) {
        __syncthreads();
#pragma unroll
        for (int t = 0; t < 8; ++t) {
            int i = w * 8 + t;
            int row = 8 * i + (lane >> 3);
            int ch  = lane & 7;
            gl_lds16(Wm + (size_t)row * CDIM + c0 + ((ch ^ (row & 7)) * 8),
                     (char*)Wl + i * 1024);
        }
        __syncthreads();

#pragma unroll
        for (int kk2 = 0; kk2 < 2; ++kk2) {
            f16x8 a[4], bf[4];
#pragma unroll
            for (int nt = 0; nt < 4; ++nt) {
                int row = nt * 16 + l15;
                int ch  = ((c0 >> 3) + kk2 * 4 + l4) ^ (row & 7);
                a[nt] = *(const f16x8*)((const char*)Xl + row * 512 + ch * 16);
            }
#pragma unroll
            for (int ot = 0; ot < 4; ++ot) {
                int row = w * 64 + ot * 16 + l15;
                int ch  = (kk2 * 4 + l4) ^ (row & 7);
                bf[ot] = *(const f16x8*)((const char*)Wl + row * 128 + ch * 16);
            }
#pragma unroll
            for (int nt = 0; nt < 4; ++nt)
#pragma unroll
                for (int ot = 0; ot < 4; ++ot)
                    acc[nt * 4 + ot] = MFMA16(a[nt], bf[ot], acc[nt * 4 + ot]);
        }
    }

    __syncthreads();

    if (mode <= 1) {
        _Float16* Dl = (_Float16*)sm;
#pragma unroll
        for (int nt = 0; nt < 4; ++nt)
#pragma unroll
            for (int ot = 0; ot < 4; ++ot)
#pragma unroll
                for (int reg = 0; reg < 4; ++reg)
                    Dl[(nt * 16 + 4 * l4 + reg) * 256 + w * 64 + ot * 16 + l15] =
                        (_Float16)(acc[nt * 4 + ot][reg] + bias_o[ot]);
        __syncthreads();
        char* dst = (char*)(OUT + ((size_t)b * NTOK + n0) * CDIM);
#pragma unroll
        for (int u = 0; u < 8; ++u) {
            f16x8 v = *(const f16x8*)((const char*)Dl + u * 4096 + tid * 16);
            *(f16x8*)(dst + u * 4096 + tid * 16) = v;
        }
    } else {
        _Float16* Dlv = (_Float16*)sm;   // [256][80]
#pragma unroll
        for (int nt = 0; nt < 4; ++nt)
#pragma unroll
            for (int ot = 0; ot < 4; ++ot)
#pragma unroll
                for (int reg = 0; reg < 4; ++reg)
                    Dlv[(w * 64 + ot * 16 + l15) * 80 + nt * 16 + 4 * l4 + reg] =
                        (_Float16)(acc[nt * 4 + ot][reg] + bias_o[ot]);
        __syncthreads();
#pragma unroll
        for (int t = 0; t < 8; ++t) {
            int ro = (w * 8 + t) * 8 + (lane >> 3);
            f16x8 v = *(const f16x8*)((const char*)Dlv + ro * 160 + (lane & 7) * 16);
            *(f16x8*)(OUT + ((size_t)b * CDIM + ro) * NTOK + n0 + (lane & 7) * 8) = v;
        }
    }
}

// ---------------------------------------------------------------------------
// Split-KV MFMA flash attention — DOUBLE-BUFFERED (2-phase pipeline).
// LDS: buf0 {Kl,Vl} 64KB | buf1 {Kl,Vl} 64KB | P 16KB  = 144KB -> 1 blk/CU.
// Iteration t: issue STAGE(tile t+1 -> buf^1) BEFORE computing buf; the
// __syncthreads() drain then lands after ~600+ cycles of MFMA/softmax.
// Main-loop math identical to rounds 2-5 (verified). pacc: PLAIN linear stores.
// ---------------------------------------------------------------------------
template <int SEG>
__global__ __launch_bounds__(512, 2) void attn_fa(
    const _Float16* __restrict__ Q, const _Float16* __restrict__ K,
    const _Float16* __restrict__ Vt, _Float16* __restrict__ pacc,
    float2* __restrict__ pml)
{
    const int tid  = threadIdx.x;
    const int lane = tid & 63;
    const int w    = tid >> 6;
    const int l15  = lane & 15, l4 = lane >> 4;

    // bijective XCD-chunked swizzle (grid % 8 == 0)
    const int nb  = 18 * BATCH * SEG, cpx = nb / 8;
    const int bid = blockIdx.x;
    const int swz = (bid & 7) * cpx + (bid >> 3);
    const int x = swz % 18;
    const int b = (swz / 18) & 7;
    const int z = swz / 144;

    const int row0  = x * 128 + w * 16;
    const int jbase = z * (NTOK / SEG);
    const int NTILES = NTOK / SEG / 64;

    __shared__ __align__(16) char smem[147456];   // 144KB
    _Float16* Pw = (_Float16*)(smem + 131072 + w * 2048);

    const size_t kbb = (size_t)b * NTOK;
    const size_t vbb = (size_t)b * CDIM * NTOK;

    // ---- stage tile (j0) into buffer buf ----
    auto stage = [&](int j0, int buf) {
        char* Klc = smem + buf * 65536;
        char* Vlc = Klc + 32768;
#pragma unroll
        for (int t = 0; t < 4; ++t) {
            int i = w * 4 + t;
            int krow = 2 * i + (lane >> 5);
            int chunk = lane & 31;
            gl_lds16(K + (kbb + j0 + krow) * CDIM + ((chunk ^ (krow & 7)) * 8),
                     Klc + i * 1024);
        }
#pragma unroll
        for (int t = 0; t < 4; ++t) {
            int i = w * 4 + t;
            int vrow = 8 * i + (lane >> 3);
            int chunk = lane & 7;
            gl_lds16(Vt + vbb + (size_t)vrow * NTOK + j0 + ((chunk ^ (vrow & 7)) * 8),
                     Vlc + i * 1024);
        }
    };

    // Q fragments: 16 rows x 256 c (nontemporal single-use stream)
    f16x8 qa[8];
    {
        const _Float16* qb = Q + ((size_t)b * NTOK + row0 + l15) * CDIM + l4 * 8;
#pragma unroll
        for (int kk = 0; kk < 8; ++kk)
            qa[kk] = __builtin_nontemporal_load((const f16x8*)(qb + kk * 32));
    }

    f32x4 acc[16];
#pragma unroll
    for (int ct = 0; ct < 16; ++ct) acc[ct] = (f32x4){0.f, 0.f, 0.f, 0.f};
    float m[4] = {-FLT_MAX, -FLT_MAX, -FLT_MAX, -FLT_MAX};
    float l[4] = {0.f, 0.f, 0.f, 0.f};

    // prologue: stage tile 0 into buf 0
    stage(jbase, 0);
    __syncthreads();

    for (int jt = 0; jt < NTILES; ++jt) {
        const int cur = jt & 1;

        // issue next tile's loads into the other buffer (in flight during compute)
        if (jt + 1 < NTILES) stage(jbase + (jt + 1) * 64, cur ^ 1);

        const char* Klc = (const char*)smem + cur * 65536;
        const char* Vlc = Klc + 32768;

        // ---- QK^T ----
        f32x4 s[4];
#pragma unroll
        for (int nt = 0; nt < 4; ++nt) {
            const char* kb = Klc + (nt * 16 + l15) * 512;
            f32x4 sv = (f32x4){0.f, 0.f, 0.f, 0.f};
#pragma unroll
            for (int kk = 0; kk < 8; ++kk) {
                f16x8 kf = *(const f16x8*)(kb + (((kk * 4 + l4) ^ (l15 & 7)) * 16));
                sv = MFMA16(qa[kk], kf, sv);
            }
            s[nt] = sv;
        }

        // ---- online softmax, defer-max THR=8 ----
#pragma unroll
        for (int reg = 0; reg < 4; ++reg) {
            float pm = fmaxf(fmaxf(s[0][reg], s[1][reg]),
                             fmaxf(s[2][reg], s[3][reg]));
            pm = fmaxf(pm, __shfl_xor(pm, 1));
            pm = fmaxf(pm, __shfl_xor(pm, 2));
            pm = fmaxf(pm, __shfl_xor(pm, 4));
            pm = fmaxf(pm, __shfl_xor(pm, 8));
            if (pm > m[reg] + 8.f) {
                float sc = __expf(m[reg] - pm);
                m[reg] = pm;
                l[reg] *= sc;
#pragma unroll
                for (int ct = 0; ct < 16; ++ct) acc[ct][reg] *= sc;
            }
            float ps = 0.f;
            const int r = 4 * l4 + reg;
#pragma unroll
            for (int nt = 0; nt < 4; ++nt) {
                float p = __expf(s[nt][reg] - m[reg]);
                ps += p;
                int j = nt * 16 + l15;
                Pw[r * 64 + ((j >> 3) ^ (r & 7)) * 8 + (j & 7)] = (_Float16)p;
            }
            ps += __shfl_xor(ps, 1);
            ps += __shfl_xor(ps, 2);
            ps += __shfl_xor(ps, 4);
            ps += __shfl_xor(ps, 8);
            l[reg] += ps;
        }

        // wave-private P dependency: drain LDS writes, fence scheduler
        asm volatile("s_waitcnt lgkmcnt(0)" ::: "memory");
        __builtin_amdgcn_sched_barrier(0);

        // ---- PV ----
        f16x8 pa[2];
#pragma unroll
        for (int kc = 0; kc < 2; ++kc)
            pa[kc] = *(const f16x8*)((const char*)Pw + l15 * 128
                                     + (((kc * 4 + l4) ^ (l15 & 7)) * 16));
#pragma unroll
        for (int ct = 0; ct < 16; ++ct) {
            const char* vb0 = Vlc + (ct * 16 + l15) * 128;
#pragma unroll
            for (int kc = 0; kc < 2; ++kc) {
                f16x8 vb = *(const f16x8*)(vb0 + (((kc * 4 + l4) ^ (l15 & 7)) * 16));
                acc[ct] = MFMA16(pa[kc], vb, acc[ct]);
            }
        }

        // drain own staging loads (issued this iteration) + barrier:
        // next buffer fully landed, all waves done reading cur.
        __syncthreads();
    }

    // ---- epilogue: LDS-staged, plain linear 16B/lane pacc stores ----
    _Float16* stg = (_Float16*)(smem + w * 8192);
#pragma unroll
    for (int reg = 0; reg < 4; ++reg) {
        float inv = 1.f / l[reg];
        int r = 4 * l4 + reg;
#pragma unroll
        for (int ct = 0; ct < 16; ++ct)
            stg[r * 256 + ct * 16 + l15] = (_Float16)(acc[ct][reg] * inv);
        if (l15 == 0)
            pml[((size_t)z * BATCH + b) * NTOK + row0 + r] = make_float2(m[reg], l[reg]);
    }
    asm volatile("s_waitcnt lgkmcnt(0)" ::: "memory");
    __builtin_amdgcn_sched_barrier(0);
    {
        const char* stgc = (const char*)stg;
        char* dst = (char*)(pacc + ((size_t)z * BATCH + b) * NTOK * CDIM
                            + (size_t)row0 * CDIM);
#pragma unroll
        for (int u = 0; u < 8; ++u) {
            f16x8 v = *(const f16x8*)(stgc + u * 1024 + lane * 16);
            *(f16x8*)(dst + u * 1024 + lane * 16) = v;
        }
    }
}

// ---------------------------------------------------------------------------
// Merge (unchanged, verified)
// ---------------------------------------------------------------------------
template <int SEG>
__global__ __launch_bounds__(256) void merge_kernel(
    const _Float16* __restrict__ pacc, const float2* __restrict__ pml,
    float* __restrict__ out)
{
    const int tid = threadIdx.x;
    const int n0 = blockIdx.x * 64;
    const int b  = blockIdx.y;

    __shared__ float wgt[SEG][64];
    __shared__ float dinv[64];
    __shared__ float T[64][68];

    if (tid < 64) {
        int n = n0 + tid;
        float ms[SEG], ls[SEG];
#pragma unroll
        for (int s = 0; s < SEG; ++s) {
            float2 v = pml[((size_t)s * BATCH + b) * NTOK + n];
            ms[s] = v.x; ls[s] = v.y;
        }
        float M = ms[0];
#pragma unroll
        for (int s = 1; s < SEG; ++s) M = fmaxf(M, ms[s]);
        float den = 0.f;
#pragma unroll
        for (int s = 0; s < SEG; ++s) {
            float g = ls[s] * __expf(ms[s] - M);
            wgt[s][tid] = g;
            den += g;
        }
        dinv[tid] = 1.f / den;
    }
    __syncthreads();

    for (int cc = 0; cc < 4; ++cc) {
        const int nl = tid >> 2, cg = (tid & 3) * 16;
        float a[16];
#pragma unroll
        for (int u = 0; u < 16; ++u) a[u] = 0.f;
#pragma unroll
        for (int s = 0; s < SEG; ++s) {
            const _Float16* p = pacc + (((size_t)s * BATCH + b) * NTOK + n0 + nl) * CDIM
                                + cc * 64 + cg;
            f16x8 v0 = ((const f16x8*)p)[0];
            f16x8 v1 = ((const f16x8*)p)[1];
            float g = wgt[s][nl];
#pragma unroll
            for (int u = 0; u < 8; ++u) {
                a[u]     += g * (float)v0[u];
                a[8 + u] += g * (float)v1[u];
            }
        }
        float di = dinv[nl];
#pragma unroll
        for (int u = 0; u < 16; ++u) T[nl][cg + u] = a[u] * di;
        __syncthreads();

        const int cl = tid >> 2, nb2 = (tid & 3) * 16;
        float* ob = out + ((size_t)b * CDIM + cc * 64 + cl) * NTOK + n0 + nb2;
#pragma unroll
        for (int u = 0; u < 4; ++u) {
            float4 v = { T[nb2 + u * 4 + 0][cl], T[nb2 + u * 4 + 1][cl],
                         T[nb2 + u * 4 + 2][cl], T[nb2 + u * 4 + 3][cl] };
            *(float4*)&ob[u * 4] = v;
        }
        __syncthreads();
    }
}

// ---------------------------------------------------------------------------
extern "C" void kernel_launch(void* const* d_in, const int* in_sizes, int n_in,
                              void* d_out, int out_size, void* d_ws, size_t ws_size,
                              hipStream_t stream)
{
    const float* x1 = (const float*)d_in[0];
    const float* x2 = (const float*)d_in[1];
    const float* Wq = (const float*)d_in[2];
    const float* bq = (const float*)d_in[3];
    const float* Wk = (const float*)d_in[4];
    const float* bk = (const float*)d_in[5];
    const float* Wv = (const float*)d_in[6];
    const float* bv = (const float*)d_in[7];
    float* out = (float*)d_out;

    const size_t plane = (size_t)BATCH * NTOK * CDIM;   // 4,718,592
    _Float16* ws16 = (_Float16*)d_ws;
    _Float16* Q   = ws16;
    _Float16* K   = ws16 + plane;
    _Float16* Vt  = ws16 + 2 * plane;
    _Float16* Xt1 = ws16 + 3 * plane;
    _Float16* Xt2 = ws16 + 4 * plane;
    _Float16* Wh  = ws16 + 5 * plane;
    const size_t fixed16 = 5 * plane + 196608;

    auto need = [&](size_t S) {
        return fixed16 * 2 + S * plane * 2 + S * (size_t)BATCH * NTOK * 8;
    };
    const int SEG = (ws_size >= need(4)) ? 4 : (ws_size >= need(2)) ? 2 : 1;

    _Float16* pacc = ws16 + fixed16;
    float2*   pml  = (float2*)((char*)d_ws + fixed16 * 2 + (size_t)SEG * plane * 2);

    cast_w<<<dim3(192), dim3(256), 0, stream>>>(Wq, Wk, Wv, Wh);
    cast_x<<<dim3(36, 4, 16), dim3(256), 0, stream>>>(x1, x2, Xt1, Xt2);
    proj_mfma<<<dim3(36, 3, BATCH), dim3(256), 0, stream>>>(
        Xt1, Xt2, Wh, bq, bk, bv, Q, K, Vt);

    const int nb = 18 * BATCH;
    if (SEG == 4) {
        attn_fa<4><<<dim3(nb * 4), dim3(512), 0, stream>>>(Q, K, Vt, pacc, pml);
        merge_kernel<4><<<dim3(36, BATCH), dim3(256), 0, stream>>>(pacc, pml, out);
    } else if (SEG == 2) {
        attn_fa<2><<<dim3(nb * 2), dim3(512), 0, stream>>>(Q, K, Vt, pacc, pml);
        merge_kernel<2><<<dim3(36, BATCH), dim3(256), 0, stream>>>(pacc, pml, out);
    } else {
        attn_fa<1><<<dim3(nb), dim3(512), 0, stream>>>(Q, K, Vt, pacc, pml);
        merge_kernel<1><<<dim3(36, BATCH), dim3(256), 0, stream>>>(pacc, pml, out);
    }
}